// Round 5
// baseline (609.871 us; speedup 1.0000x reference)
//
#include <hip/hip_runtime.h>

#define D_OUT 4096
#define D_IN  4096
#define RANK  64
#define NNZ   1000000
#define MTOT  8192   // 4*2048
#define KDIM  4096
#define NDIM  4096

#define BM 256
#define BN 256
#define BK 64
#define NT (KDIM / BK)   // 64 K-tiles

#define SCATTER_BLOCKS ((NNZ + 255) / 256)        // 3907
#define CVT_BLOCKS     ((MTOT * KDIM / 8) / 256)  // 16384

typedef __bf16 bf16_t;
typedef __bf16 bf16x8 __attribute__((ext_vector_type(8)));
typedef __bf16 bf16x4 __attribute__((ext_vector_type(4)));
typedef float  f32x4  __attribute__((ext_vector_type(4)));

// ------- kernel 1: fused {scatter-add sparse COO into S} + {xb = bf16(x)} -----
// The two parts are independent (scatter writes S; cvt reads x, writes xb).
// Scatter is atomic/latency-bound at low BW; cvt is streaming -> overlapping
// them fills the idle HBM bandwidth under the atomic drain.
__global__ __launch_bounds__(256) void scatter_cvt_kernel(
    const float* __restrict__ vals, const int* __restrict__ idx,
    float* __restrict__ S, const float* __restrict__ x,
    bf16_t* __restrict__ xb) {
  const int t = threadIdx.x;
  if (blockIdx.x < SCATTER_BLOCKS) {
    int i = blockIdx.x * 256 + t;
    if (i < NNZ) {
      int r = idx[i];
      int c = idx[NNZ + i];
      atomicAdd(&S[(size_t)r * D_IN + c], vals[i]);
    }
    return;
  }
  // ---- cvt part: 16384 blocks * 256 threads * 8 elems ----
  int i = (blockIdx.x - SCATTER_BLOCKS) * 256 + t;
  const f32x4* p = (const f32x4*)x + (size_t)i * 2;
  f32x4 a = p[0], b = p[1];
  bf16x8 o;
  o[0] = (bf16_t)a[0]; o[1] = (bf16_t)a[1]; o[2] = (bf16_t)a[2]; o[3] = (bf16_t)a[3];
  o[4] = (bf16_t)b[0]; o[5] = (bf16_t)b[1]; o[6] = (bf16_t)b[2]; o[7] = (bf16_t)b[3];
  *((bf16x8*)xb + i) = o;
}

// ---------------- kernel 2: weffb = bf16(W + A@Bmat + S) ----------------
__global__ __launch_bounds__(256) void build_weff_kernel(
    const float* __restrict__ W, const float* __restrict__ A,
    const float* __restrict__ B, const float* __restrict__ S,
    bf16_t* __restrict__ outb) {
  __shared__ float sA[64 * 64];
  const int t = threadIdx.x;
  const int o0 = (blockIdx.x >> 5) * 64;
  const int d0 = (blockIdx.x & 31) * 128;
  const int td = t & 31;     // d-group
  const int to = t >> 5;     // o-group 0..7
  const int d  = d0 + td * 4;

  #pragma unroll
  for (int i = 0; i < 16; ++i)
    sA[t + i * 256] = A[(size_t)o0 * 64 + t + i * 256];
  __syncthreads();

  f32x4 acc[8] = {};
  for (int r = 0; r < 64; ++r) {
    f32x4 bv = *(const f32x4*)&B[(size_t)r * D_IN + d];
    #pragma unroll
    for (int j = 0; j < 8; ++j) {
      float a = sA[(to * 8 + j) * 64 + r];
      acc[j] += a * bv;
    }
  }

  #pragma unroll
  for (int j = 0; j < 8; ++j) {
    int o = o0 + to * 8 + j;
    size_t idx = (size_t)o * D_IN + d;
    f32x4 wv = *(const f32x4*)&W[idx];
    f32x4 sv = *(const f32x4*)&S[idx];
    f32x4 v  = wv + sv + acc[j];
    bf16x4 ob;
    ob[0] = (bf16_t)v[0]; ob[1] = (bf16_t)v[1];
    ob[2] = (bf16_t)v[2]; ob[3] = (bf16_t)v[3];
    *(bf16x4*)&outb[idx] = ob;
  }
}

// ---------------- kernel 3: 256x256 8-phase deep-pipelined GEMM ----------------
// out[M][N] = Xb[M][K] @ Wb[N][K]^T, bf16 in / f32 out.
// R5: 2 K-tiles per loop iteration -> CUR/NXT are compile-time, LDS addresses
// fold to base+immediate, longer scheduler window (m201's literal structure).
// Schedule per K-tile unchanged from R4 (verified: conflicts 0, MfmaUtil 45.6%).
//
// Per K-tile (4 phases, stage tile t+1 into other buffer):
//  P0: rd ks0 A[0-3]+B | stage ks0.h0 (A,B)       | bar lgkm0 | 16 MFMA | bar
//  P1: rd ks0 A[4-7]   | stage ks0.h1 (A,B) vm(4) | bar lgkm0 | 16 MFMA | bar
//  P2: rd ks1 A[0-3]+B | stage ks1.h0 (A,B)       | bar lgkm0 | 16 MFMA | bar
//  P3: rd ks1 A[4-7]   | stage ks1.h1 (A,B) vm(4) | bar lgkm0 | 16 MFMA | bar
// P1's vmcnt(4) completes this tile's ks1 (needed at P2); P3's completes next
// tile's ks0. Never vmcnt(0) in the main loop.

#define SBAR()   __builtin_amdgcn_sched_barrier(0)
#define VMCNT4() do { asm volatile("s_waitcnt vmcnt(4)"); SBAR(); } while (0)
#define VMCNT0() do { asm volatile("s_waitcnt vmcnt(0)"); SBAR(); } while (0)
#define LGKM0()  do { asm volatile("s_waitcnt lgkmcnt(0)"); SBAR(); } while (0)
#define BARR()   do { SBAR(); __builtin_amdgcn_s_barrier(); SBAR(); } while (0)

__global__ __launch_bounds__(512, 2) void gemm256_kernel(
    const bf16_t* __restrict__ Xb, const bf16_t* __restrict__ Wb,
    float* __restrict__ out) {
  // [buf][A=0/B=1][ks 0/1][h 0/1][row 0..127][k 0..31]  = 128 KiB
  __shared__ bf16_t lds[2][2][2][2][128][32];

  const int t    = threadIdx.x;
  const int w    = t >> 6;
  const int lane = t & 63;
  const int lr   = lane & 15;
  const int lq   = lane >> 4;
  // T2: swizzled 16B-slot index for fragment reads (elems offset)
  const int kofs = (lq ^ ((lr >> 1) & 3)) * 8;

  // T1: XCD-aware swizzle over the 512-block grid (512 % 8 == 0 -> simple form)
  const int bid  = blockIdx.x;
  const int wgid = (bid & 7) * 64 + (bid >> 3);
  const int m0 = (wgid >> 4) * BM;   // 32 m-tiles (consecutive wgids share m-panel)
  const int n0 = (wgid & 15) * BN;   // 16 n-tiles

  const int wm = (w >> 2) * 128;     // 2 M-wave-rows
  const int wn = (w & 3) * 64;       // 4 N-wave-cols
  const int wmh = wm >> 7;           // A h-index for this wave
  const int wnh = wn >> 7;           // B h-index for this wave
  const int wnr = wn & 64;           // B row base within h-half

  // staging: thread t owns (row = t>>2, swizzled 16B k-slice) of each op.
  // Source slice g = (t&3) ^ ((t>>3)&3) so that LDS slot s of row r holds
  // global slice s ^ ((r>>1)&3); LDS dest stays linear (t*16B).
  const int srow = t >> 2;
  const int sg   = (((t & 3) ^ ((t >> 3) & 3))) * 8;  // global k-slice, elems
  const int sd   = (t & 3) * 8;                       // linear LDS slot, elems
  const bf16_t* aSrc = Xb + (size_t)(m0 + srow) * KDIM + sg;
  const bf16_t* bSrc = Wb + (size_t)(n0 + srow) * KDIM + sg;

#define STAGE(NXT, MAT, KS, H, TKN)                                            \
  __builtin_amdgcn_global_load_lds(                                            \
      (const __attribute__((address_space(1))) void*)(const void*)             \
          (((MAT) ? bSrc : aSrc) + (size_t)(H) * 128 * KDIM                    \
           + (size_t)(TKN) * BK + (KS) * 32),                                  \
      (__attribute__((address_space(3))) void*)(void*)                         \
          &lds[NXT][MAT][KS][H][srow][sd],                                     \
      16, 0, 0)

#define RD_A(IB, CUR, KS) do {                                                 \
    _Pragma("unroll")                                                          \
    for (int i_ = 0; i_ < 4; ++i_)                                             \
      av[i_] = *(const bf16x8*)&lds[CUR][0][KS][wmh]                           \
                   [((IB) + i_) * 16 + lr][kofs];                              \
  } while (0)
#define RD_B(CUR, KS) do {                                                     \
    _Pragma("unroll")                                                          \
    for (int j_ = 0; j_ < 4; ++j_)                                             \
      bv[j_] = *(const bf16x8*)&lds[CUR][1][KS][wnh]                           \
                   [wnr + j_ * 16 + lr][kofs];                                 \
  } while (0)

#define MFMA_BLOCK(IB) do {                                                    \
    __builtin_amdgcn_s_setprio(1);                                             \
    _Pragma("unroll")                                                          \
    for (int i_ = 0; i_ < 4; ++i_)                                             \
      _Pragma("unroll")                                                        \
      for (int j_ = 0; j_ < 4; ++j_)                                           \
        acc[(IB) + i_][j_] = __builtin_amdgcn_mfma_f32_16x16x32_bf16(          \
            av[i_], bv[j_], acc[(IB) + i_][j_], 0, 0, 0);                      \
    __builtin_amdgcn_s_setprio(0);                                             \
  } while (0)

#define GEMM_TILE(CUR, NXT, TKN, STG) do {                                     \
    /* P0 */                                                                   \
    RD_A(0, CUR, 0); RD_B(CUR, 0);                                             \
    if (STG) { STAGE(NXT, 0, 0, 0, TKN); STAGE(NXT, 1, 0, 0, TKN); }           \
    BARR(); LGKM0();                                                           \
    MFMA_BLOCK(0);                                                             \
    BARR();                                                                    \
    /* P1 */                                                                   \
    RD_A(4, CUR, 0);                                                           \
    if (STG) { STAGE(NXT, 0, 0, 1, TKN); STAGE(NXT, 1, 0, 1, TKN); VMCNT4(); } \
    else     { VMCNT0(); }                                                     \
    BARR(); LGKM0();                                                           \
    MFMA_BLOCK(4);                                                             \
    BARR();                                                                    \
    /* P2 */                                                                   \
    RD_A(0, CUR, 1); RD_B(CUR, 1);                                             \
    if (STG) { STAGE(NXT, 0, 1, 0, TKN); STAGE(NXT, 1, 1, 0, TKN); }           \
    BARR(); LGKM0();                                                           \
    MFMA_BLOCK(0);                                                             \
    BARR();                                                                    \
    /* P3 */                                                                   \
    RD_A(4, CUR, 1);                                                           \
    if (STG) { STAGE(NXT, 0, 1, 1, TKN); STAGE(NXT, 1, 1, 1, TKN); VMCNT4(); } \
    BARR(); LGKM0();                                                           \
    MFMA_BLOCK(4);                                                             \
    BARR();                                                                    \
  } while (0)

  f32x4 acc[8][4] = {};
  bf16x8 av[4], bv[4];

  // prologue: stage tile 0 (ks0 ops first), keep ks1 ops in flight
  STAGE(0, 0, 0, 0, 0); STAGE(0, 1, 0, 0, 0);
  STAGE(0, 0, 0, 1, 0); STAGE(0, 1, 0, 1, 0);
  STAGE(0, 0, 1, 0, 0); STAGE(0, 1, 1, 0, 0);
  STAGE(0, 0, 1, 1, 0); STAGE(0, 1, 1, 1, 0);
  VMCNT4();
  BARR();

  // 2 K-tiles per iteration: all buffer indices compile-time.
  // tiles 0..61 computed in the loop; tile 62 + 63 in the tail.
  for (int tk = 0; tk < NT - 2; tk += 2) {
    GEMM_TILE(0, 1, tk + 1, 1);
    GEMM_TILE(1, 0, tk + 2, 1);
  }
  GEMM_TILE(0, 1, NT - 1, 1);   // compute tile 62 (buf0), stage tile 63
  GEMM_TILE(1, 0, 0, 0);        // compute tile 63 (buf1), no staging

  // C-write: C row = lq*4+rr, C col = lr (verified layout)
  #pragma unroll
  for (int i = 0; i < 8; ++i)
    #pragma unroll
    for (int j = 0; j < 4; ++j)
      #pragma unroll
      for (int rr = 0; rr < 4; ++rr) {
        int mm = m0 + wm + i * 16 + lq * 4 + rr;
        int nn = n0 + wn + j * 16 + lr;
        out[(size_t)mm * NDIM + nn] = acc[i][j][rr];
      }

#undef STAGE
#undef RD_A
#undef RD_B
#undef MFMA_BLOCK
#undef GEMM_TILE
}

extern "C" void kernel_launch(void* const* d_in, const int* in_sizes, int n_in,
                              void* d_out, int out_size, void* d_ws, size_t ws_size,
                              hipStream_t stream) {
  const float* x  = (const float*)d_in[0];   // [4,2048,4096] fp32
  const float* W  = (const float*)d_in[1];   // [4096,4096]
  const float* A  = (const float*)d_in[2];   // [4096,64]
  const float* B  = (const float*)d_in[3];   // [64,4096]
  const float* sv = (const float*)d_in[4];   // [1e6]
  const int*   si = (const int*)d_in[5];     // [2,1e6]
  float* out = (float*)d_out;

  // workspace: S f32 (64MB) | weff bf16 (32MB) | x bf16 (64MB)
  float*  S     = (float*)d_ws;
  bf16_t* weffb = (bf16_t*)(S + (size_t)D_OUT * D_IN);
  bf16_t* xb    = weffb + (size_t)D_OUT * D_IN;

  hipMemsetAsync(S, 0, (size_t)D_OUT * D_IN * sizeof(float), stream);
  // fused: scatter (atomic-bound) overlapped with x cvt (streaming)
  scatter_cvt_kernel<<<SCATTER_BLOCKS + CVT_BLOCKS, 256, 0, stream>>>(
      sv, si, S, x, xb);
  build_weff_kernel<<<32 * 64, 256, 0, stream>>>(W, A, B, S, weffb);
  gemm256_kernel<<<dim3((MTOT / BM) * (NDIM / BN)), 512, 0, stream>>>(xb, weffb, out);
}